// Round 11
// baseline (90.625 us; speedup 1.0000x reference)
//
#include <hip/hip_runtime.h>

#define AA_NUM 21
#define A_NUM  14
#define NPTS   4096    // 16^3
#define BLK    512     // lane pair per (x,y) column; h=t&1 owns 8 z's (4 packed pairs)

typedef float v2 __attribute__((ext_vector_type(2)));

// Broadcast a block-uniform float into an SGPR.
__device__ __forceinline__ float rfl(float x) {
    return __int_as_float(__builtin_amdgcn_readfirstlane(__float_as_int(x)));
}

// Packed fast inverse sqrt: bit-hack seed (full-rate int ops) + 1 packed Newton
// step. Replaces 2x v_rsq_f32 (quarter/eighth-rate trans) with full-rate issue.
// Max rel err ~0.175% -- validation margin is 400x (absmax 3.9e-3 vs 1.56).
__device__ __forceinline__ v2 fast_rsq2(v2 x) {
    v2 y;
    y.x = __int_as_float(0x5f3759df - (__float_as_int(x.x) >> 1));
    y.y = __int_as_float(0x5f3759df - (__float_as_int(x.y) >> 1));
    v2 t = x * y;               // pk_mul
    t = t * y;                  // pk_mul   t = x*y^2
    v2 u = (v2)(1.5f) - (v2)(0.5f) * t;   // pk_fma(t, -0.5, 1.5)
    return y * u;               // pk_mul
}

__global__ __launch_bounds__(BLK, 8) void preproc_kernel(
    const float* __restrict__ Cin,   // [ZN][14][3] f32
    const int*   __restrict__ Lin,   // [ZN] i32
    const float* __restrict__ Min,   // [ZN][14] f32 atom_mask
    const float* __restrict__ Qin,   // [21][14] f32 charges
    float*       __restrict__ out,   // f32: Cb | div | frames
    int ZN)
{
    __shared__ float s_fx[16][256];  // [z][col] — lane-pair 2-way bank alias: free
    __shared__ float s_fy[16][256];

    const int n = blockIdx.x;
    const int t = threadIdx.x;
    const int col = t >> 1;          // 0..255
    const int h   = t & 1;           // z half
    const int xi  = col >> 4;        // 0..15
    const int yi  = col & 15;        // 0..15
    const size_t div_off = (size_t)ZN * 12;
    const size_t fr_off  = div_off + (size_t)ZN * NPTS;

    // ---- block-uniform inputs -> scalar loads ----
    const float* c = Cin + (size_t)n * A_NUM * 3;
    int la = Lin[n];
    la = (la == -1) ? (AA_NUM - 1) : la;
    const float* qrow = Qin + la * A_NUM;
    const float* mrow = Min + (size_t)n * A_NUM;

    // ---- frames (redundant per-thread on uniform data) ----
    // NOTE: the reference's x = x_raw - dot(x_raw,y_unit) is a SCALAR broadcast
    // subtract -> the basis is NON-orthogonal. d^2 must be computed in WORLD
    // space (R9's frame-space decomposition failed for exactly this reason).
    const float c0 = 0.58273431f, c1 = 0.56802827f, c2 = 0.54067466f;
    float n0x = c[0], n0y = c[1], n0z = c[2];
    float cax = c[3], cay = c[4], caz = c[5];
    float ccx = c[6], ccy = c[7], ccz = c[8];
    float b1x = cax - n0x, b1y = cay - n0y, b1z = caz - n0z;
    float b2x = ccx - cax, b2y = ccy - cay, b2z = ccz - caz;
    float b3x = b1y * b2z - b1z * b2y;
    float b3y = b1z * b2x - b1x * b2z;
    float b3z = b1x * b2y - b1y * b2x;
    float cbx = cax - c0 * b2x + c1 * b1x - c2 * b3x;
    float cby = cay - c0 * b2y + c1 * b1y - c2 * b3y;
    float cbz = caz - c0 * b2z + c1 * b1z - c2 * b3z;

    float yx = cbx - cax, yy = cby - cay, yz = cbz - caz;
    float yr = 1.0f / fmaxf(sqrtf(yx * yx + yy * yy + yz * yz), 1e-6f);
    float yux = yx * yr, yuy = yy * yr, yuz = yz * yr;
    float xrx = ccx - n0x, xry = ccy - n0y, xrz = ccz - n0z;
    float xp = xrx * yux + xry * yuy + xrz * yuz;   // scalar broadcast, per reference
    float xx = xrx - xp, xy = xry - xp, xz = xrz - xp;
    float xr = 1.0f / fmaxf(sqrtf(xx * xx + xy * xy + xz * xz), 1e-6f);
    float xux = xx * xr, xuy = xy * xr, xuz = xz * xr;
    float zx = xuy * yuz - xuz * yuy;
    float zy = xuz * yux - xux * yuz;
    float zz = xux * yuy - xuy * yux;
    float zr = 1.0f / fmaxf(sqrtf(zx * zx + zy * zy + zz * zz), 1e-6f);
    float zux = zx * zr, zuy = zy * zr, zuz = zz * zr;

    if (t == 0) {
        float* po = out + (size_t)n * 12;
        po[0]  = n0x; po[1]  = n0y; po[2]  = n0z;
        po[3]  = cax; po[4]  = cay; po[5]  = caz;
        po[6]  = ccx; po[7]  = ccy; po[8]  = ccz;
        po[9]  = cbx; po[10] = cby; po[11] = cbz;
        float* pf = out + fr_off + (size_t)n * 9;
        pf[0] = xux; pf[1] = xuy; pf[2] = xuz;
        pf[3] = yux; pf[4] = yuy; pf[5] = yuz;
        pf[6] = zux; pf[7] = zuy; pf[8] = zuz;
    }

    // frame rows + origin pinned to SGPRs
    float fr0 = rfl(xux), fr1 = rfl(xuy), fr2 = rfl(xuz);
    float fr3 = rfl(yux), fr4 = rfl(yuy), fr5 = rfl(yuz);
    float fr6 = rfl(zux), fr7 = rfl(zuy), fr8 = rfl(zuz);
    float orx = rfl(cbx), ory = rfl(cby), orz = rfl(cbz);

    // atoms + pre-masked charges pinned to SGPRs
    float ax[A_NUM], ay[A_NUM], az[A_NUM], aq[A_NUM];
    #pragma unroll
    for (int a = 0; a < A_NUM; ++a) {
        ax[a] = rfl(c[a * 3 + 0]);
        ay[a] = rfl(c[a * 3 + 1]);
        az[a] = rfl(c[a * 3 + 2]);
        aq[a] = rfl(qrow[a] * mrow[a]);
    }

    // ---- this thread's column + z half ----
    const float vx = (float)xi - 8.0f;
    const float vy = (float)yi - 4.0f;
    const float bpx = orx + vx * fr0 + vy * fr3;
    const float bpy = ory + vx * fr1 + vy * fr4;
    const float bpz = orz + vx * fr2 + vy * fr5;
    const int zbase = h << 3;

    float fzv[8];

    // ---- field: 4 packed z-pairs, world space, guards removed (validated R8) ----
    #pragma unroll
    for (int p = 0; p < 4; ++p) {
        v2 vz = (v2){ (float)(zbase + 2 * p) - 8.0f, (float)(zbase + 2 * p + 1) - 8.0f };
        v2 px = (v2)(bpx) + vz * (v2)(fr6);
        v2 py = (v2)(bpy) + vz * (v2)(fr7);
        v2 pz = (v2)(bpz) + vz * (v2)(fr8);
        v2 fx = (v2)(0.0f), fy = (v2)(0.0f), fz = (v2)(0.0f);
        #pragma unroll
        for (int a = 0; a < A_NUM; ++a) {
            v2 dx = px - (v2)(ax[a]);
            v2 dy = py - (v2)(ay[a]);
            v2 dz = pz - (v2)(az[a]);
            v2 d2 = dx * dx + dy * dy + dz * dz;     // pk mul + 2 pk fma
            v2 rq = fast_rsq2(d2);                   // 1/d (NR, no trans op)
            v2 mn;
            mn.x = fminf(rq.x, 1.0f);
            mn.y = fminf(rq.y, 1.0f);
            v2 w = (v2)(aq[a]) * (rq * (mn * mn));   // aq/(d*max(d,1)^2)
            fx += w * dx;
            fy += w * dy;
            fz += w * dz;
        }
        // per-point normalize + store (hardware rsq fine here: 8 per thread total)
        #pragma unroll
        for (int k = 0; k < 2; ++k) {
            float ffx = k ? fx.y : fx.x;
            float ffy = k ? fy.y : fy.x;
            float ffz = k ? fz.y : fz.x;
            float rf = __builtin_amdgcn_rsqf(ffx * ffx + ffy * ffy + ffz * ffz);
            int zi_ = zbase + 2 * p + k;
            s_fx[zi_][col] = ffx * rf;
            s_fy[zi_][col] = ffy * rf;
            fzv[2 * p + k] = ffz * rf;
        }
    }

    // cross-half fz halo: h=0 needs partner z=8 (its fzv[0]); h=1 needs z=7 (fzv[7])
    float halo = __shfl_xor(h ? fzv[0] : fzv[7], 1);

    __syncthreads();

    const int cxp = col + ((xi < 15) ? 16 : 0);
    const int cxm = col - ((xi > 0)  ? 16 : 0);
    const int cyp = col + ((yi < 15) ? 1  : 0);
    const int cym = col - ((yi > 0)  ? 1  : 0);
    const float sx = (xi > 0 && xi < 15) ? 0.5f : 1.0f;
    const float sy = (yi > 0 && yi < 15) ? 0.5f : 1.0f;

    float dv[8];
    #pragma unroll
    for (int i = 0; i < 8; ++i) {
        int z = zbase + i;
        float up = (i < 7) ? fzv[i + 1] : (h ? fzv[7] : halo);
        float dn = (i > 0) ? fzv[i - 1] : (h ? halo : fzv[0]);
        float sz = (z > 0 && z < 15) ? 0.5f : 1.0f;
        float dzv = (up - dn) * sz;
        float dxv = (s_fx[z][cxp] - s_fx[z][cxm]) * sx;
        float dyv = (s_fy[z][cyp] - s_fy[z][cym]) * sy;
        dv[i] = dxv + dyv + dzv;
    }

    float4* dout = (float4*)(out + div_off + (size_t)n * NPTS + col * 16 + (h << 3));
    dout[0] = make_float4(dv[0], dv[1], dv[2], dv[3]);
    dout[1] = make_float4(dv[4], dv[5], dv[6], dv[7]);
}

extern "C" void kernel_launch(void* const* d_in, const int* in_sizes, int n_in,
                              void* d_out, int out_size, void* d_ws, size_t ws_size,
                              hipStream_t stream) {
    const float* C = (const float*)d_in[0];
    const int*   L = (const int*)d_in[1];
    const float* M = (const float*)d_in[2];
    const float* Q = (const float*)d_in[3];
    float* out = (float*)d_out;
    const int ZN = in_sizes[1];   // L has one entry per residue
    preproc_kernel<<<dim3(ZN), dim3(BLK), 0, stream>>>(C, L, M, Q, out, ZN);
}

// Round 12
// 88.430 us; speedup vs baseline: 1.0248x; 1.0248x over previous
//
#include <hip/hip_runtime.h>

#define AA_NUM 21
#define A_NUM  14
#define NPTS   4096    // 16^3
#define BLK    512     // lane pair per (x,y) column; h=t&1 owns 8 z's (4 packed pairs)

typedef float v2 __attribute__((ext_vector_type(2)));

// Broadcast a block-uniform float into an SGPR.
__device__ __forceinline__ float rfl(float x) {
    return __int_as_float(__builtin_amdgcn_readfirstlane(__float_as_int(x)));
}

// R11 post-mortem: NR bit-hack rsq was issue-neutral (+1.3 us) and cost 100x
// accuracy (absmax 0.36 vs 0.0039). Hardware v_rsq_f32 restored (R10 state,
// best measured: dur_us 89.295, reproduced twice to ~ns).

__global__ __launch_bounds__(BLK, 8) void preproc_kernel(
    const float* __restrict__ Cin,   // [ZN][14][3] f32
    const int*   __restrict__ Lin,   // [ZN] i32
    const float* __restrict__ Min,   // [ZN][14] f32 atom_mask
    const float* __restrict__ Qin,   // [21][14] f32 charges
    float*       __restrict__ out,   // f32: Cb | div | frames
    int ZN)
{
    __shared__ float s_fx[16][256];  // [z][col] — lane-pair 2-way bank alias: free
    __shared__ float s_fy[16][256];

    const int n = blockIdx.x;
    const int t = threadIdx.x;
    const int col = t >> 1;          // 0..255
    const int h   = t & 1;           // z half
    const int xi  = col >> 4;        // 0..15
    const int yi  = col & 15;        // 0..15
    const size_t div_off = (size_t)ZN * 12;
    const size_t fr_off  = div_off + (size_t)ZN * NPTS;

    // ---- block-uniform inputs -> scalar loads ----
    const float* c = Cin + (size_t)n * A_NUM * 3;
    int la = Lin[n];
    la = (la == -1) ? (AA_NUM - 1) : la;
    const float* qrow = Qin + la * A_NUM;
    const float* mrow = Min + (size_t)n * A_NUM;

    // ---- frames (redundant per-thread on uniform data) ----
    // NOTE: the reference's x = x_raw - dot(x_raw,y_unit) is a SCALAR broadcast
    // subtract -> the basis is NON-orthogonal. d^2 must be computed in WORLD
    // space (R9's frame-space decomposition failed for exactly this reason).
    const float c0 = 0.58273431f, c1 = 0.56802827f, c2 = 0.54067466f;
    float n0x = c[0], n0y = c[1], n0z = c[2];
    float cax = c[3], cay = c[4], caz = c[5];
    float ccx = c[6], ccy = c[7], ccz = c[8];
    float b1x = cax - n0x, b1y = cay - n0y, b1z = caz - n0z;
    float b2x = ccx - cax, b2y = ccy - cay, b2z = ccz - caz;
    float b3x = b1y * b2z - b1z * b2y;
    float b3y = b1z * b2x - b1x * b2z;
    float b3z = b1x * b2y - b1y * b2x;
    float cbx = cax - c0 * b2x + c1 * b1x - c2 * b3x;
    float cby = cay - c0 * b2y + c1 * b1y - c2 * b3y;
    float cbz = caz - c0 * b2z + c1 * b1z - c2 * b3z;

    float yx = cbx - cax, yy = cby - cay, yz = cbz - caz;
    float yr = 1.0f / fmaxf(sqrtf(yx * yx + yy * yy + yz * yz), 1e-6f);
    float yux = yx * yr, yuy = yy * yr, yuz = yz * yr;
    float xrx = ccx - n0x, xry = ccy - n0y, xrz = ccz - n0z;
    float xp = xrx * yux + xry * yuy + xrz * yuz;   // scalar broadcast, per reference
    float xx = xrx - xp, xy = xry - xp, xz = xrz - xp;
    float xr = 1.0f / fmaxf(sqrtf(xx * xx + xy * xy + xz * xz), 1e-6f);
    float xux = xx * xr, xuy = xy * xr, xuz = xz * xr;
    float zx = xuy * yuz - xuz * yuy;
    float zy = xuz * yux - xux * yuz;
    float zz = xux * yuy - xuy * yux;
    float zr = 1.0f / fmaxf(sqrtf(zx * zx + zy * zy + zz * zz), 1e-6f);
    float zux = zx * zr, zuy = zy * zr, zuz = zz * zr;

    if (t == 0) {
        float* po = out + (size_t)n * 12;
        po[0]  = n0x; po[1]  = n0y; po[2]  = n0z;
        po[3]  = cax; po[4]  = cay; po[5]  = caz;
        po[6]  = ccx; po[7]  = ccy; po[8]  = ccz;
        po[9]  = cbx; po[10] = cby; po[11] = cbz;
        float* pf = out + fr_off + (size_t)n * 9;
        pf[0] = xux; pf[1] = xuy; pf[2] = xuz;
        pf[3] = yux; pf[4] = yuy; pf[5] = yuz;
        pf[6] = zux; pf[7] = zuy; pf[8] = zuz;
    }

    // frame rows + origin pinned to SGPRs
    float fr0 = rfl(xux), fr1 = rfl(xuy), fr2 = rfl(xuz);
    float fr3 = rfl(yux), fr4 = rfl(yuy), fr5 = rfl(yuz);
    float fr6 = rfl(zux), fr7 = rfl(zuy), fr8 = rfl(zuz);
    float orx = rfl(cbx), ory = rfl(cby), orz = rfl(cbz);

    // atoms + pre-masked charges pinned to SGPRs
    float ax[A_NUM], ay[A_NUM], az[A_NUM], aq[A_NUM];
    #pragma unroll
    for (int a = 0; a < A_NUM; ++a) {
        ax[a] = rfl(c[a * 3 + 0]);
        ay[a] = rfl(c[a * 3 + 1]);
        az[a] = rfl(c[a * 3 + 2]);
        aq[a] = rfl(qrow[a] * mrow[a]);
    }

    // ---- this thread's column + z half ----
    const float vx = (float)xi - 8.0f;
    const float vy = (float)yi - 4.0f;
    const float bpx = orx + vx * fr0 + vy * fr3;
    const float bpy = ory + vx * fr1 + vy * fr4;
    const float bpz = orz + vx * fr2 + vy * fr5;
    const int zbase = h << 3;

    float fzv[8];

    // ---- field: 4 packed z-pairs, world space, guards removed (validated R8) ----
    #pragma unroll
    for (int p = 0; p < 4; ++p) {
        v2 vz = (v2){ (float)(zbase + 2 * p) - 8.0f, (float)(zbase + 2 * p + 1) - 8.0f };
        v2 px = (v2)(bpx) + vz * (v2)(fr6);
        v2 py = (v2)(bpy) + vz * (v2)(fr7);
        v2 pz = (v2)(bpz) + vz * (v2)(fr8);
        v2 fx = (v2)(0.0f), fy = (v2)(0.0f), fz = (v2)(0.0f);
        #pragma unroll
        for (int a = 0; a < A_NUM; ++a) {
            v2 dx = px - (v2)(ax[a]);
            v2 dy = py - (v2)(ay[a]);
            v2 dz = pz - (v2)(az[a]);
            v2 d2 = dx * dx + dy * dy + dz * dz;     // pk mul + 2 pk fma
            v2 rq, mn;
            rq.x = __builtin_amdgcn_rsqf(d2.x);      // 1/d
            rq.y = __builtin_amdgcn_rsqf(d2.y);
            mn.x = fminf(rq.x, 1.0f);
            mn.y = fminf(rq.y, 1.0f);
            v2 w = (v2)(aq[a]) * (rq * (mn * mn));   // aq/(d*max(d,1)^2)
            fx += w * dx;
            fy += w * dy;
            fz += w * dz;
        }
        // per-point normalize + store (world components already)
        #pragma unroll
        for (int k = 0; k < 2; ++k) {
            float ffx = k ? fx.y : fx.x;
            float ffy = k ? fy.y : fy.x;
            float ffz = k ? fz.y : fz.x;
            float rf = __builtin_amdgcn_rsqf(ffx * ffx + ffy * ffy + ffz * ffz);
            int zi_ = zbase + 2 * p + k;
            s_fx[zi_][col] = ffx * rf;
            s_fy[zi_][col] = ffy * rf;
            fzv[2 * p + k] = ffz * rf;
        }
    }

    // cross-half fz halo: h=0 needs partner z=8 (its fzv[0]); h=1 needs z=7 (fzv[7])
    float halo = __shfl_xor(h ? fzv[0] : fzv[7], 1);

    __syncthreads();

    const int cxp = col + ((xi < 15) ? 16 : 0);
    const int cxm = col - ((xi > 0)  ? 16 : 0);
    const int cyp = col + ((yi < 15) ? 1  : 0);
    const int cym = col - ((yi > 0)  ? 1  : 0);
    const float sx = (xi > 0 && xi < 15) ? 0.5f : 1.0f;
    const float sy = (yi > 0 && yi < 15) ? 0.5f : 1.0f;

    float dv[8];
    #pragma unroll
    for (int i = 0; i < 8; ++i) {
        int z = zbase + i;
        float up = (i < 7) ? fzv[i + 1] : (h ? fzv[7] : halo);
        float dn = (i > 0) ? fzv[i - 1] : (h ? halo : fzv[0]);
        float sz = (z > 0 && z < 15) ? 0.5f : 1.0f;
        float dzv = (up - dn) * sz;
        float dxv = (s_fx[z][cxp] - s_fx[z][cxm]) * sx;
        float dyv = (s_fy[z][cyp] - s_fy[z][cym]) * sy;
        dv[i] = dxv + dyv + dzv;
    }

    float4* dout = (float4*)(out + div_off + (size_t)n * NPTS + col * 16 + (h << 3));
    dout[0] = make_float4(dv[0], dv[1], dv[2], dv[3]);
    dout[1] = make_float4(dv[4], dv[5], dv[6], dv[7]);
}

extern "C" void kernel_launch(void* const* d_in, const int* in_sizes, int n_in,
                              void* d_out, int out_size, void* d_ws, size_t ws_size,
                              hipStream_t stream) {
    const float* C = (const float*)d_in[0];
    const int*   L = (const int*)d_in[1];
    const float* M = (const float*)d_in[2];
    const float* Q = (const float*)d_in[3];
    float* out = (float*)d_out;
    const int ZN = in_sizes[1];   // L has one entry per residue
    preproc_kernel<<<dim3(ZN), dim3(BLK), 0, stream>>>(C, L, M, Q, out, ZN);
}